// Round 1
// baseline (1712.521 us; speedup 1.0000x reference)
//
#include <hip/hip_runtime.h>
#include <stdint.h>
#include <math.h>

#define B_ 32
#define V_ 2048
#define E_ 12288
#define M_ (B_*V_)

typedef __bf16 bf16x8 __attribute__((ext_vector_type(8)));
typedef float f32x4 __attribute__((ext_vector_type(4)));

__device__ __forceinline__ float bf2f(unsigned short u){
  union { unsigned int i; float f; } v; v.i = ((unsigned int)u) << 16; return v.f;
}
__device__ __forceinline__ unsigned short f2bf(float f){
  union { float f; unsigned int i; } v; v.f = f;
  unsigned int r = (v.i + 0x7fffu + ((v.i >> 16) & 1u)) >> 16;
  return (unsigned short)r;
}

// ---------------- CSR build ----------------
__global__ void k_deg(const int* __restrict__ ei, int* __restrict__ deg){
  int e = blockIdx.x * 256 + threadIdx.x;
  if (e < E_) atomicAdd(&deg[ei[E_ + e]], 1);   // dst side
}

// single wave: exclusive scan of per-vertex counts -> rowptr; also dinv, selfw
__global__ void k_scan(const int* __restrict__ cnt, int* __restrict__ rowptr,
                       float* __restrict__ dinv, float* __restrict__ selfw){
  int lane = threadIdx.x;      // 64 threads
  int base = lane * 32;
  int local[32]; int s = 0;
  #pragma unroll
  for (int i = 0; i < 32; i++){ local[i] = cnt[base + i]; s += local[i]; }
  int pre = s;
  for (int off = 1; off < 64; off <<= 1){
    int t = __shfl_up(pre, off);
    if (lane >= off) pre += t;
  }
  pre -= s;  // exclusive
  int run = pre;
  #pragma unroll
  for (int i = 0; i < 32; i++){
    rowptr[base + i] = run; run += local[i];
    float d = (float)(local[i] + 1);          // + self loop
    float di = rsqrtf(d);
    dinv[base + i] = di;
    selfw[base + i] = di * di;
  }
  if (lane == 63) rowptr[V_] = run;
}

__global__ void k_scatter(const int* __restrict__ ei, const int* __restrict__ rowptr,
                          int* __restrict__ fill, int* __restrict__ cols,
                          float* __restrict__ vals, const float* __restrict__ dinv){
  int e = blockIdx.x * 256 + threadIdx.x;
  if (e < E_){
    int s = ei[e], d = ei[E_ + e];
    int pos = rowptr[d] + atomicAdd(&fill[d], 1);
    cols[pos] = s;
    vals[pos] = dinv[s] * dinv[d];
  }
}

// ---------------- weight convert: Wt[n*K+k] = bf16(W[k*N+n]) ----------------
__global__ void k_wt(const float* __restrict__ W, unsigned short* __restrict__ Wt,
                     int K, int N){
  int id = blockIdx.x * 256 + threadIdx.x;
  if (id < K * N){
    int n = id / K, k = id % K;
    Wt[id] = f2bf(W[(size_t)k * N + n]);
  }
}

// ---------------- imgw[b,f] = img[b,:] @ W1[3:,:] ----------------
__global__ void k_imgw(const float* __restrict__ img, const float* __restrict__ W1,
                       float* __restrict__ imgw){
  int id = blockIdx.x * 256 + threadIdx.x;   // 32*512
  int b = id >> 9, f = id & 511;
  const float* w = W1 + 3 * 512 + f;
  const float* x = img + b * 512;
  float acc = 0.f;
  #pragma unroll 4
  for (int k = 0; k < 512; k++) acc += x[k] * w[(size_t)k * 512];
  imgw[id] = acc;
}

// ---------------- layer1 fused: transform(K=3) + img-broadcast + agg + bias ----------------
__global__ __launch_bounds__(256) void k_layer1(
    const float* __restrict__ vert, const float* __restrict__ W1,
    const float* __restrict__ b1, const float* __restrict__ imgw,
    const int* __restrict__ rowptr, const int* __restrict__ cols,
    const float* __restrict__ vals, const float* __restrict__ selfw,
    unsigned short* __restrict__ X){
  int blk = blockIdx.x;            // b*V + dst
  int b = blk >> 11, dst = blk & (V_ - 1);
  int f = threadIdx.x * 2;
  const float* vb = vert + (size_t)b * V_ * 3;
  float w00 = W1[f],        w01 = W1[f + 1];
  float w10 = W1[512 + f],  w11 = W1[512 + f + 1];
  float w20 = W1[1024 + f], w21 = W1[1024 + f + 1];
  float sw = selfw[dst];
  float wsum = sw;
  float a0, a1;
  { const float* p = vb + dst * 3;
    float x0 = p[0], x1 = p[1], x2 = p[2];
    a0 = sw * (x0 * w00 + x1 * w10 + x2 * w20);
    a1 = sw * (x0 * w01 + x1 * w11 + x2 * w21); }
  int rs = rowptr[dst], re = rowptr[dst + 1];
  for (int e = rs; e < re; e++){
    int s = cols[e]; float v = vals[e]; wsum += v;
    const float* p = vb + s * 3;
    float x0 = p[0], x1 = p[1], x2 = p[2];
    a0 += v * (x0 * w00 + x1 * w10 + x2 * w20);
    a1 += v * (x0 * w01 + x1 * w11 + x2 * w21);
  }
  a0 += wsum * imgw[b * 512 + f]     + b1[f];
  a1 += wsum * imgw[b * 512 + f + 1] + b1[f + 1];
  unsigned int packed = (unsigned int)f2bf(a0) | ((unsigned int)f2bf(a1) << 16);
  ((unsigned int*)X)[(size_t)blk * 256 + threadIdx.x] = packed;
}

// ---------------- bf16 MFMA GEMM: Hg[M,N] = Xg[M,K] @ W  (W given transposed as Wt[N,K]) ----------------
template<int BM, int BN, int WM, int WN, int TM, int TN>
__global__ __launch_bounds__(WM*WN*64) void k_gemm(
    const unsigned short* __restrict__ Xg, const unsigned short* __restrict__ Wt,
    unsigned short* __restrict__ Hg, int K, int N){
  constexpr int BK = 32;
  constexpr int LDA = BK + 8;   // pad -> conflict-free ds_read_b128
  __shared__ __align__(16) unsigned short As[BM * LDA];
  __shared__ __align__(16) unsigned short Bs[BN * LDA];
  const int tid = threadIdx.x;
  const int row0 = blockIdx.x * BM, col0 = blockIdx.y * BN;
  const int wave = tid >> 6, lane = tid & 63;
  const int wr = wave / WN, wc = wave % WN;
  const int lrow = lane & 15, lq = lane >> 4;
  f32x4 acc[TM][TN] = {};
  constexpr int NT  = WM * WN * 64;
  constexpr int NCA = (BM * 4) / NT;
  constexpr int NCB = (BN * 4) / NT;
  for (int k0 = 0; k0 < K; k0 += BK){
    __syncthreads();
    #pragma unroll
    for (int i = 0; i < NCA; i++){
      int c = tid + i * NT;
      int m = c >> 2, kk = (c & 3) << 3;
      *(uint4*)&As[m * LDA + kk] = *(const uint4*)&Xg[(size_t)(row0 + m) * K + k0 + kk];
    }
    #pragma unroll
    for (int i = 0; i < NCB; i++){
      int c = tid + i * NT;
      int n = c >> 2, kk = (c & 3) << 3;
      *(uint4*)&Bs[n * LDA + kk] = *(const uint4*)&Wt[(size_t)(col0 + n) * K + k0 + kk];
    }
    __syncthreads();
    bf16x8 af[TM], bfr[TN];
    #pragma unroll
    for (int tm = 0; tm < TM; tm++)
      af[tm] = *(const bf16x8*)&As[(wr * TM * 16 + tm * 16 + lrow) * LDA + lq * 8];
    #pragma unroll
    for (int tn = 0; tn < TN; tn++)
      bfr[tn] = *(const bf16x8*)&Bs[(wc * TN * 16 + tn * 16 + lrow) * LDA + lq * 8];
    #pragma unroll
    for (int tm = 0; tm < TM; tm++)
      #pragma unroll
      for (int tn = 0; tn < TN; tn++)
        acc[tm][tn] = __builtin_amdgcn_mfma_f32_16x16x32_bf16(af[tm], bfr[tn], acc[tm][tn], 0, 0, 0);
  }
  #pragma unroll
  for (int tm = 0; tm < TM; tm++){
    #pragma unroll
    for (int tn = 0; tn < TN; tn++){
      int col = col0 + wc * TN * 16 + tn * 16 + lrow;
      #pragma unroll
      for (int r = 0; r < 4; r++){
        int row = row0 + wr * TM * 16 + tm * 16 + lq * 4 + r;
        Hg[(size_t)row * N + col] = f2bf(acc[tm][tn][r]);
      }
    }
  }
}

// ---------------- aggregation: Xo[b,dst,:] = maybe_relu(selfw*H[dst] + sum val*H[src] + bias) ----------------
template<int F, int NTHR>
__global__ __launch_bounds__(NTHR) void k_agg(
    const unsigned short* __restrict__ Hg, const float* __restrict__ bias,
    const int* __restrict__ rowptr, const int* __restrict__ cols,
    const float* __restrict__ vals, const float* __restrict__ selfw,
    unsigned short* __restrict__ Xo, int relu){
  constexpr int VPT = F / NTHR;   // 2 (F=512) or 1 (F=64)
  int blk = blockIdx.x;
  int b = blk >> 11, dst = blk & (V_ - 1);
  int tid = threadIdx.x;
  const unsigned short* hb = Hg + (size_t)b * V_ * F;
  float sw = selfw[dst];
  float acc0, acc1 = 0.f;
  if (VPT == 2){
    unsigned int u = ((const unsigned int*)(hb + (size_t)dst * F))[tid];
    acc0 = sw * bf2f(u & 0xffff); acc1 = sw * bf2f(u >> 16);
  } else {
    acc0 = sw * bf2f(hb[(size_t)dst * F + tid]);
  }
  int rs = rowptr[dst], re = rowptr[dst + 1];
  for (int e = rs; e < re; e++){
    int s = cols[e]; float v = vals[e];
    if (VPT == 2){
      unsigned int u = ((const unsigned int*)(hb + (size_t)s * F))[tid];
      acc0 += v * bf2f(u & 0xffff); acc1 += v * bf2f(u >> 16);
    } else {
      acc0 += v * bf2f(hb[(size_t)s * F + tid]);
    }
  }
  if (VPT == 2){
    acc0 += bias[tid * 2]; acc1 += bias[tid * 2 + 1];
    if (relu){ acc0 = fmaxf(acc0, 0.f); acc1 = fmaxf(acc1, 0.f); }
    ((unsigned int*)(Xo + (size_t)blk * F))[tid] =
        (unsigned int)f2bf(acc0) | ((unsigned int)f2bf(acc1) << 16);
  } else {
    acc0 += bias[tid];
    if (relu) acc0 = fmaxf(acc0, 0.f);
    Xo[(size_t)blk * F + tid] = f2bf(acc0);
  }
}

// ---------------- layer6: h6 = x5 @ W6 (K=64, N=3), then agg+bias+relu ----------------
__global__ void k_l6(const unsigned short* __restrict__ x5, const float* __restrict__ W6,
                     float* __restrict__ h6){
  int id = blockIdx.x * 256 + threadIdx.x;   // M_ threads
  const unsigned short* xr = x5 + (size_t)id * 64;
  float a0 = 0.f, a1 = 0.f, a2 = 0.f;
  #pragma unroll 8
  for (int k = 0; k < 64; k++){
    float x = bf2f(xr[k]);
    a0 += x * W6[k * 3 + 0]; a1 += x * W6[k * 3 + 1]; a2 += x * W6[k * 3 + 2];
  }
  h6[(size_t)id * 3 + 0] = a0; h6[(size_t)id * 3 + 1] = a1; h6[(size_t)id * 3 + 2] = a2;
}

__global__ void k_agg6(const float* __restrict__ h6, const float* __restrict__ b6,
                       const int* __restrict__ rowptr, const int* __restrict__ cols,
                       const float* __restrict__ vals, const float* __restrict__ selfw,
                       float* __restrict__ xf){
  int id = blockIdx.x * 256 + threadIdx.x;   // M_ threads, one per (b,dst)
  int b = id >> 11, dst = id & (V_ - 1);
  const float* hb = h6 + (size_t)b * V_ * 3;
  float sw = selfw[dst];
  float a0 = sw * hb[dst * 3], a1 = sw * hb[dst * 3 + 1], a2 = sw * hb[dst * 3 + 2];
  int rs = rowptr[dst], re = rowptr[dst + 1];
  for (int e = rs; e < re; e++){
    int s = cols[e]; float v = vals[e];
    a0 += v * hb[s * 3]; a1 += v * hb[s * 3 + 1]; a2 += v * hb[s * 3 + 2];
  }
  a0 = fmaxf(a0 + b6[0], 0.f); a1 = fmaxf(a1 + b6[1], 0.f); a2 = fmaxf(a2 + b6[2], 0.f);
  xf[(size_t)id * 3 + 0] = a0; xf[(size_t)id * 3 + 1] = a1; xf[(size_t)id * 3 + 2] = a2;
}

// ---------------- FC: thread per (b,n). mode 1 => out = vert + 0.1*tanh(acc+bias) ----------------
__global__ void k_fc(const float* __restrict__ in, const float* __restrict__ W,
                     const float* __restrict__ bias, float* __restrict__ out,
                     int K, int N, int mode, const float* __restrict__ vert){
  int id = blockIdx.x * 256 + threadIdx.x;
  int b = id / N, n = id % N;
  const float* x = in + (size_t)b * K;
  const float* w = W + n;
  float acc = 0.f;
  for (int k = 0; k < K; k += 4){
    acc += x[k]     * w[(size_t)k * N]
         + x[k + 1] * w[(size_t)(k + 1) * N]
         + x[k + 2] * w[(size_t)(k + 2) * N]
         + x[k + 3] * w[(size_t)(k + 3) * N];
  }
  acc += bias[n];
  if (mode == 1) acc = vert[id] + 0.1f * tanhf(acc);
  out[id] = acc;
}

// ---------------- workspace layout ----------------
static constexpr size_t AL(size_t x){ return (x + 255) & ~(size_t)255; }
static constexpr size_t OX    = 0;
static constexpr size_t OH    = OX    + AL((size_t)M_ * 512 * 2);
static constexpr size_t OX5   = OH    + AL((size_t)M_ * 512 * 2);
static constexpr size_t OH6   = OX5   + AL((size_t)M_ * 64 * 2);
static constexpr size_t OXF   = OH6   + AL((size_t)M_ * 3 * 4);
static constexpr size_t OFC1  = OXF   + AL((size_t)M_ * 3 * 4);
static constexpr size_t OFC2  = OFC1  + AL((size_t)B_ * 1024 * 4);
static constexpr size_t OW2T  = OFC2  + AL((size_t)B_ * 1024 * 4);
static constexpr size_t OW3T  = OW2T  + AL((size_t)512 * 512 * 2);
static constexpr size_t OW4T  = OW3T  + AL((size_t)512 * 512 * 2);
static constexpr size_t OW5T  = OW4T  + AL((size_t)512 * 512 * 2);
static constexpr size_t OIMG  = OW5T  + AL((size_t)512 * 64 * 2);
static constexpr size_t ODEG  = OIMG  + AL((size_t)B_ * 512 * 4);
static constexpr size_t OCNT  = ODEG  + AL((size_t)V_ * 4);      // adjacent to ODEG: one memset
static constexpr size_t OROW  = OCNT  + AL((size_t)V_ * 4);
static constexpr size_t OCOL  = OROW  + AL((size_t)(V_ + 1) * 4);
static constexpr size_t OVAL  = OCOL  + AL((size_t)E_ * 4);
static constexpr size_t OSELF = OVAL  + AL((size_t)E_ * 4);
static constexpr size_t ODINV = OSELF + AL((size_t)V_ * 4);

extern "C" void kernel_launch(void* const* d_in, const int* in_sizes, int n_in,
                              void* d_out, int out_size, void* d_ws, size_t ws_size,
                              hipStream_t stream){
  const float* vert  = (const float*)d_in[0];
  const float* img   = (const float*)d_in[1];
  const int*   ei    = (const int*)  d_in[2];
  const float* W1 = (const float*)d_in[3],  *b1 = (const float*)d_in[4];
  const float* W2 = (const float*)d_in[5],  *b2 = (const float*)d_in[6];
  const float* W3 = (const float*)d_in[7],  *b3 = (const float*)d_in[8];
  const float* W4 = (const float*)d_in[9],  *b4 = (const float*)d_in[10];
  const float* W5 = (const float*)d_in[11], *b5 = (const float*)d_in[12];
  const float* W6 = (const float*)d_in[13], *b6 = (const float*)d_in[14];
  const float* fcW1 = (const float*)d_in[15], *fcb1 = (const float*)d_in[16];
  const float* fcW2 = (const float*)d_in[17], *fcb2 = (const float*)d_in[18];
  const float* fcW3 = (const float*)d_in[19], *fcb3 = (const float*)d_in[20];
  float* out = (float*)d_out;

  char* ws = (char*)d_ws;
  unsigned short* X   = (unsigned short*)(ws + OX);
  unsigned short* H   = (unsigned short*)(ws + OH);
  unsigned short* X5  = (unsigned short*)(ws + OX5);
  float* H6   = (float*)(ws + OH6);
  float* XF   = (float*)(ws + OXF);
  float* FC1o = (float*)(ws + OFC1);
  float* FC2o = (float*)(ws + OFC2);
  unsigned short* W2T = (unsigned short*)(ws + OW2T);
  unsigned short* W3T = (unsigned short*)(ws + OW3T);
  unsigned short* W4T = (unsigned short*)(ws + OW4T);
  unsigned short* W5T = (unsigned short*)(ws + OW5T);
  float* IMG  = (float*)(ws + OIMG);
  int*   DEG  = (int*)(ws + ODEG);
  int*   CNT  = (int*)(ws + OCNT);
  int*   ROW  = (int*)(ws + OROW);
  int*   COL  = (int*)(ws + OCOL);
  float* VAL  = (float*)(ws + OVAL);
  float* SELF = (float*)(ws + OSELF);
  float* DINV = (float*)(ws + ODINV);

  // CSR build
  hipMemsetAsync(ws + ODEG, 0, OCNT - ODEG + AL((size_t)V_ * 4), stream);
  k_deg<<<(E_ + 255) / 256, 256, 0, stream>>>(ei, DEG);
  k_scan<<<1, 64, 0, stream>>>(DEG, ROW, DINV, SELF);
  k_scatter<<<(E_ + 255) / 256, 256, 0, stream>>>(ei, ROW, CNT, COL, VAL, DINV);

  // weight transposes (bf16)
  k_wt<<<(512 * 512 + 255) / 256, 256, 0, stream>>>(W2, W2T, 512, 512);
  k_wt<<<(512 * 512 + 255) / 256, 256, 0, stream>>>(W3, W3T, 512, 512);
  k_wt<<<(512 * 512 + 255) / 256, 256, 0, stream>>>(W4, W4T, 512, 512);
  k_wt<<<(512 * 64  + 255) / 256, 256, 0, stream>>>(W5, W5T, 512, 64);

  // layer 1 (fused transform + agg)
  k_imgw<<<(B_ * 512) / 256, 256, 0, stream>>>(img, W1, IMG);
  k_layer1<<<M_, 256, 0, stream>>>(vert, W1, b1, IMG, ROW, COL, VAL, SELF, X);

  // layers 2-4: GEMM 512x512 + agg (relu after 2 and 4)
  k_gemm<128,128,2,2,4,4><<<dim3(M_ / 128, 4), 256, 0, stream>>>(X, W2T, H, 512, 512);
  k_agg<512,256><<<M_, 256, 0, stream>>>(H, b2, ROW, COL, VAL, SELF, X, 1);
  k_gemm<128,128,2,2,4,4><<<dim3(M_ / 128, 4), 256, 0, stream>>>(X, W3T, H, 512, 512);
  k_agg<512,256><<<M_, 256, 0, stream>>>(H, b3, ROW, COL, VAL, SELF, X, 0);
  k_gemm<128,128,2,2,4,4><<<dim3(M_ / 128, 4), 256, 0, stream>>>(X, W4T, H, 512, 512);
  k_agg<512,256><<<M_, 256, 0, stream>>>(H, b4, ROW, COL, VAL, SELF, X, 1);

  // layer 5: GEMM 512->64 + agg
  k_gemm<128,64,4,1,2,4><<<dim3(M_ / 128, 1), 256, 0, stream>>>(X, W5T, H, 512, 64);
  k_agg<64,64><<<M_, 64, 0, stream>>>(H, b5, ROW, COL, VAL, SELF, X5, 0);

  // layer 6: 64->3 + agg + relu
  k_l6<<<M_ / 256, 256, 0, stream>>>(X5, W6, H6);
  k_agg6<<<M_ / 256, 256, 0, stream>>>(H6, b6, ROW, COL, VAL, SELF, XF);

  // FC head
  k_fc<<<(B_ * 1024) / 256, 256, 0, stream>>>(XF,   fcW1, fcb1, FC1o, 6144, 1024, 0, nullptr);
  k_fc<<<(B_ * 1024) / 256, 256, 0, stream>>>(FC1o, fcW2, fcb2, FC2o, 1024, 1024, 0, nullptr);
  k_fc<<<(B_ * 6144) / 256, 256, 0, stream>>>(FC2o, fcW3, fcb3, out,  1024, 6144, 1, vert);
}

// Round 2
// 952.961 us; speedup vs baseline: 1.7971x; 1.7971x over previous
//
#include <hip/hip_runtime.h>
#include <stdint.h>
#include <math.h>

#define B_ 32
#define V_ 2048
#define E_ 12288
#define M_ (B_*V_)

typedef __bf16 bf16x8 __attribute__((ext_vector_type(8)));
typedef float f32x4 __attribute__((ext_vector_type(4)));

__device__ __forceinline__ float bf2f(unsigned short u){
  union { unsigned int i; float f; } v; v.i = ((unsigned int)u) << 16; return v.f;
}
__device__ __forceinline__ unsigned short f2bf(float f){
  union { float f; unsigned int i; } v; v.f = f;
  unsigned int r = (v.i + 0x7fffu + ((v.i >> 16) & 1u)) >> 16;
  return (unsigned short)r;
}

// ---------------- CSR build ----------------
__global__ void k_deg(const int* __restrict__ ei, int* __restrict__ deg){
  int e = blockIdx.x * 256 + threadIdx.x;
  if (e < E_) atomicAdd(&deg[ei[E_ + e]], 1);   // dst side
}

// single wave: exclusive scan of per-vertex counts -> rowptr; also dinv, selfw
__global__ void k_scan(const int* __restrict__ cnt, int* __restrict__ rowptr,
                       float* __restrict__ dinv, float* __restrict__ selfw){
  int lane = threadIdx.x;      // 64 threads
  int base = lane * 32;
  int local[32]; int s = 0;
  #pragma unroll
  for (int i = 0; i < 32; i++){ local[i] = cnt[base + i]; s += local[i]; }
  int pre = s;
  for (int off = 1; off < 64; off <<= 1){
    int t = __shfl_up(pre, off);
    if (lane >= off) pre += t;
  }
  pre -= s;  // exclusive
  int run = pre;
  #pragma unroll
  for (int i = 0; i < 32; i++){
    rowptr[base + i] = run; run += local[i];
    float d = (float)(local[i] + 1);          // + self loop
    float di = rsqrtf(d);
    dinv[base + i] = di;
    selfw[base + i] = di * di;
  }
  if (lane == 63) rowptr[V_] = run;
}

__global__ void k_scatter(const int* __restrict__ ei, const int* __restrict__ rowptr,
                          int* __restrict__ fill, int* __restrict__ cols,
                          float* __restrict__ vals, const float* __restrict__ dinv){
  int e = blockIdx.x * 256 + threadIdx.x;
  if (e < E_){
    int s = ei[e], d = ei[E_ + e];
    int pos = rowptr[d] + atomicAdd(&fill[d], 1);
    cols[pos] = s;
    vals[pos] = dinv[s] * dinv[d];
  }
}

// ---------------- weight convert: Wt[n*K+k] = bf16(W[k*N+n]) ----------------
__global__ void k_wt(const float* __restrict__ W, unsigned short* __restrict__ Wt,
                     int K, int N){
  int id = blockIdx.x * 256 + threadIdx.x;
  if (id < K * N){
    int n = id / K, k = id % K;
    Wt[id] = f2bf(W[(size_t)k * N + n]);
  }
}

// ---------------- imgw[b,f] = img[b,:] @ W1[3:,:] ----------------
__global__ void k_imgw(const float* __restrict__ img, const float* __restrict__ W1,
                       float* __restrict__ imgw){
  int id = blockIdx.x * 256 + threadIdx.x;   // 32*512
  int b = id >> 9, f = id & 511;
  const float* w = W1 + 3 * 512 + f;
  const float* x = img + b * 512;
  float acc = 0.f;
  #pragma unroll 4
  for (int k = 0; k < 512; k++) acc += x[k] * w[(size_t)k * 512];
  imgw[id] = acc;
}

// ---------------- layer1 fused: transform(K=3) + img-broadcast + agg + bias ----------------
__global__ __launch_bounds__(256) void k_layer1(
    const float* __restrict__ vert, const float* __restrict__ W1,
    const float* __restrict__ b1, const float* __restrict__ imgw,
    const int* __restrict__ rowptr, const int* __restrict__ cols,
    const float* __restrict__ vals, const float* __restrict__ selfw,
    unsigned short* __restrict__ X){
  int blk = blockIdx.x;            // b*V + dst
  int b = blk >> 11, dst = blk & (V_ - 1);
  int f = threadIdx.x * 2;
  const float* vb = vert + (size_t)b * V_ * 3;
  float w00 = W1[f],        w01 = W1[f + 1];
  float w10 = W1[512 + f],  w11 = W1[512 + f + 1];
  float w20 = W1[1024 + f], w21 = W1[1024 + f + 1];
  float sw = selfw[dst];
  float wsum = sw;
  float a0, a1;
  { const float* p = vb + dst * 3;
    float x0 = p[0], x1 = p[1], x2 = p[2];
    a0 = sw * (x0 * w00 + x1 * w10 + x2 * w20);
    a1 = sw * (x0 * w01 + x1 * w11 + x2 * w21); }
  int rs = rowptr[dst], re = rowptr[dst + 1];
  for (int e = rs; e < re; e++){
    int s = cols[e]; float v = vals[e]; wsum += v;
    const float* p = vb + s * 3;
    float x0 = p[0], x1 = p[1], x2 = p[2];
    a0 += v * (x0 * w00 + x1 * w10 + x2 * w20);
    a1 += v * (x0 * w01 + x1 * w11 + x2 * w21);
  }
  a0 += wsum * imgw[b * 512 + f]     + b1[f];
  a1 += wsum * imgw[b * 512 + f + 1] + b1[f + 1];
  unsigned int packed = (unsigned int)f2bf(a0) | ((unsigned int)f2bf(a1) << 16);
  ((unsigned int*)X)[(size_t)blk * 256 + threadIdx.x] = packed;
}

// ---------------- bf16 MFMA GEMM: Hg[M,N] = Xg[M,K] @ W  (W given transposed as Wt[N,K]) ----------------
template<int BM, int BN, int WM, int WN, int TM, int TN>
__global__ __launch_bounds__(WM*WN*64) void k_gemm(
    const unsigned short* __restrict__ Xg, const unsigned short* __restrict__ Wt,
    unsigned short* __restrict__ Hg, int K, int N){
  constexpr int BK = 32;
  constexpr int LDA = BK + 8;   // pad -> conflict-free ds_read_b128
  __shared__ __align__(16) unsigned short As[BM * LDA];
  __shared__ __align__(16) unsigned short Bs[BN * LDA];
  const int tid = threadIdx.x;
  const int row0 = blockIdx.x * BM, col0 = blockIdx.y * BN;
  const int wave = tid >> 6, lane = tid & 63;
  const int wr = wave / WN, wc = wave % WN;
  const int lrow = lane & 15, lq = lane >> 4;
  f32x4 acc[TM][TN] = {};
  constexpr int NT  = WM * WN * 64;
  constexpr int NCA = (BM * 4) / NT;
  constexpr int NCB = (BN * 4) / NT;
  for (int k0 = 0; k0 < K; k0 += BK){
    __syncthreads();
    #pragma unroll
    for (int i = 0; i < NCA; i++){
      int c = tid + i * NT;
      int m = c >> 2, kk = (c & 3) << 3;
      *(uint4*)&As[m * LDA + kk] = *(const uint4*)&Xg[(size_t)(row0 + m) * K + k0 + kk];
    }
    #pragma unroll
    for (int i = 0; i < NCB; i++){
      int c = tid + i * NT;
      int n = c >> 2, kk = (c & 3) << 3;
      *(uint4*)&Bs[n * LDA + kk] = *(const uint4*)&Wt[(size_t)(col0 + n) * K + k0 + kk];
    }
    __syncthreads();
    bf16x8 af[TM], bfr[TN];
    #pragma unroll
    for (int tm = 0; tm < TM; tm++)
      af[tm] = *(const bf16x8*)&As[(wr * TM * 16 + tm * 16 + lrow) * LDA + lq * 8];
    #pragma unroll
    for (int tn = 0; tn < TN; tn++)
      bfr[tn] = *(const bf16x8*)&Bs[(wc * TN * 16 + tn * 16 + lrow) * LDA + lq * 8];
    #pragma unroll
    for (int tm = 0; tm < TM; tm++)
      #pragma unroll
      for (int tn = 0; tn < TN; tn++)
        acc[tm][tn] = __builtin_amdgcn_mfma_f32_16x16x32_bf16(af[tm], bfr[tn], acc[tm][tn], 0, 0, 0);
  }
  #pragma unroll
  for (int tm = 0; tm < TM; tm++){
    #pragma unroll
    for (int tn = 0; tn < TN; tn++){
      int col = col0 + wc * TN * 16 + tn * 16 + lrow;
      #pragma unroll
      for (int r = 0; r < 4; r++){
        int row = row0 + wr * TM * 16 + tm * 16 + lq * 4 + r;
        Hg[(size_t)row * N + col] = f2bf(acc[tm][tn][r]);
      }
    }
  }
}

// ---------------- aggregation: Xo[b,dst,:] = maybe_relu(selfw*H[dst] + sum val*H[src] + bias) ----------------
template<int F, int NTHR>
__global__ __launch_bounds__(NTHR) void k_agg(
    const unsigned short* __restrict__ Hg, const float* __restrict__ bias,
    const int* __restrict__ rowptr, const int* __restrict__ cols,
    const float* __restrict__ vals, const float* __restrict__ selfw,
    unsigned short* __restrict__ Xo, int relu){
  constexpr int VPT = F / NTHR;   // 2 (F=512) or 1 (F=64)
  int blk = blockIdx.x;
  int b = blk >> 11, dst = blk & (V_ - 1);
  int tid = threadIdx.x;
  const unsigned short* hb = Hg + (size_t)b * V_ * F;
  float sw = selfw[dst];
  float acc0, acc1 = 0.f;
  if (VPT == 2){
    unsigned int u = ((const unsigned int*)(hb + (size_t)dst * F))[tid];
    acc0 = sw * bf2f(u & 0xffff); acc1 = sw * bf2f(u >> 16);
  } else {
    acc0 = sw * bf2f(hb[(size_t)dst * F + tid]);
  }
  int rs = rowptr[dst], re = rowptr[dst + 1];
  for (int e = rs; e < re; e++){
    int s = cols[e]; float v = vals[e];
    if (VPT == 2){
      unsigned int u = ((const unsigned int*)(hb + (size_t)s * F))[tid];
      acc0 += v * bf2f(u & 0xffff); acc1 += v * bf2f(u >> 16);
    } else {
      acc0 += v * bf2f(hb[(size_t)s * F + tid]);
    }
  }
  if (VPT == 2){
    acc0 += bias[tid * 2]; acc1 += bias[tid * 2 + 1];
    if (relu){ acc0 = fmaxf(acc0, 0.f); acc1 = fmaxf(acc1, 0.f); }
    ((unsigned int*)(Xo + (size_t)blk * F))[tid] =
        (unsigned int)f2bf(acc0) | ((unsigned int)f2bf(acc1) << 16);
  } else {
    acc0 += bias[tid];
    if (relu) acc0 = fmaxf(acc0, 0.f);
    Xo[(size_t)blk * F + tid] = f2bf(acc0);
  }
}

// ---------------- layer6: h6 = x5 @ W6 (K=64, N=3), then agg+bias+relu ----------------
__global__ void k_l6(const unsigned short* __restrict__ x5, const float* __restrict__ W6,
                     float* __restrict__ h6){
  int id = blockIdx.x * 256 + threadIdx.x;   // M_ threads
  const unsigned short* xr = x5 + (size_t)id * 64;
  float a0 = 0.f, a1 = 0.f, a2 = 0.f;
  #pragma unroll 8
  for (int k = 0; k < 64; k++){
    float x = bf2f(xr[k]);
    a0 += x * W6[k * 3 + 0]; a1 += x * W6[k * 3 + 1]; a2 += x * W6[k * 3 + 2];
  }
  h6[(size_t)id * 3 + 0] = a0; h6[(size_t)id * 3 + 1] = a1; h6[(size_t)id * 3 + 2] = a2;
}

__global__ void k_agg6(const float* __restrict__ h6, const float* __restrict__ b6,
                       const int* __restrict__ rowptr, const int* __restrict__ cols,
                       const float* __restrict__ vals, const float* __restrict__ selfw,
                       float* __restrict__ xf){
  int id = blockIdx.x * 256 + threadIdx.x;   // M_ threads, one per (b,dst)
  int b = id >> 11, dst = id & (V_ - 1);
  const float* hb = h6 + (size_t)b * V_ * 3;
  float sw = selfw[dst];
  float a0 = sw * hb[dst * 3], a1 = sw * hb[dst * 3 + 1], a2 = sw * hb[dst * 3 + 2];
  int rs = rowptr[dst], re = rowptr[dst + 1];
  for (int e = rs; e < re; e++){
    int s = cols[e]; float v = vals[e];
    a0 += v * hb[s * 3]; a1 += v * hb[s * 3 + 1]; a2 += v * hb[s * 3 + 2];
  }
  a0 = fmaxf(a0 + b6[0], 0.f); a1 = fmaxf(a1 + b6[1], 0.f); a2 = fmaxf(a2 + b6[2], 0.f);
  xf[(size_t)id * 3 + 0] = a0; xf[(size_t)id * 3 + 1] = a1; xf[(size_t)id * 3 + 2] = a2;
}

// ---------------- FC split-K stage A: partial[ks][b][n] = x[b, k-chunk] @ W[k-chunk, n] ----------------
// One block: 256-wide n stripe x KC-deep k chunk, ALL 32 batch rows (32 accs/thread).
// x loads are wave-uniform -> scalar loads on the SMEM pipe; W loads coalesced, each
// element touched exactly once grid-wide.
template<int KC>
__global__ __launch_bounds__(256) void k_fcp(
    const float* __restrict__ in, const float* __restrict__ W,
    float* __restrict__ partial, int K, int N){
  const int n = blockIdx.x * 256 + threadIdx.x;
  const int k0 = blockIdx.y * KC;
  float acc[B_] = {};
  for (int kk = 0; kk < KC; kk += 4){
    const float* wp = W + (size_t)(k0 + kk) * N + n;
    float w0 = wp[0];
    float w1 = wp[(size_t)N];
    float w2 = wp[(size_t)2 * N];
    float w3 = wp[(size_t)3 * N];
    #pragma unroll
    for (int b = 0; b < B_; b++){
      const float* xp = in + (size_t)b * K + k0 + kk;   // uniform -> s_load
      acc[b] += xp[0] * w0 + xp[1] * w1 + xp[2] * w2 + xp[3] * w3;
    }
  }
  float* p = partial + (size_t)blockIdx.y * B_ * N + n;
  #pragma unroll
  for (int b = 0; b < B_; b++) p[(size_t)b * N] = acc[b];
}

// ---------------- FC split-K stage B: reduce partials + bias (+ final tanh) ----------------
__global__ __launch_bounds__(256) void k_fcr(
    const float* __restrict__ partial, const float* __restrict__ bias,
    float* __restrict__ out, int N, int KS, int mode, const float* __restrict__ vert){
  int id = blockIdx.x * 256 + threadIdx.x;   // B_*N threads
  int n = id & (N - 1);                      // N is power of two (1024) or 6144? -> use %
  n = id % N;
  float acc = bias[n];
  for (int s = 0; s < KS; s++) acc += partial[(size_t)s * B_ * N + id];
  if (mode) acc = vert[id] + 0.1f * tanhf(acc);
  out[id] = acc;
}

// ---------------- workspace layout ----------------
static constexpr size_t AL(size_t x){ return (x + 255) & ~(size_t)255; }
static constexpr size_t OX    = 0;
static constexpr size_t OH    = OX    + AL((size_t)M_ * 512 * 2);   // also reused as FC partial buffer
static constexpr size_t OX5   = OH    + AL((size_t)M_ * 512 * 2);
static constexpr size_t OH6   = OX5   + AL((size_t)M_ * 64 * 2);
static constexpr size_t OXF   = OH6   + AL((size_t)M_ * 3 * 4);
static constexpr size_t OFC1  = OXF   + AL((size_t)M_ * 3 * 4);
static constexpr size_t OFC2  = OFC1  + AL((size_t)B_ * 1024 * 4);
static constexpr size_t OW2T  = OFC2  + AL((size_t)B_ * 1024 * 4);
static constexpr size_t OW3T  = OW2T  + AL((size_t)512 * 512 * 2);
static constexpr size_t OW4T  = OW3T  + AL((size_t)512 * 512 * 2);
static constexpr size_t OW5T  = OW4T  + AL((size_t)512 * 512 * 2);
static constexpr size_t OIMG  = OW5T  + AL((size_t)512 * 64 * 2);
static constexpr size_t ODEG  = OIMG  + AL((size_t)B_ * 512 * 4);
static constexpr size_t OCNT  = ODEG  + AL((size_t)V_ * 4);      // adjacent to ODEG: one memset
static constexpr size_t OROW  = OCNT  + AL((size_t)V_ * 4);
static constexpr size_t OCOL  = OROW  + AL((size_t)(V_ + 1) * 4);
static constexpr size_t OVAL  = OCOL  + AL((size_t)E_ * 4);
static constexpr size_t OSELF = OVAL  + AL((size_t)E_ * 4);
static constexpr size_t ODINV = OSELF + AL((size_t)V_ * 4);

extern "C" void kernel_launch(void* const* d_in, const int* in_sizes, int n_in,
                              void* d_out, int out_size, void* d_ws, size_t ws_size,
                              hipStream_t stream){
  const float* vert  = (const float*)d_in[0];
  const float* img   = (const float*)d_in[1];
  const int*   ei    = (const int*)  d_in[2];
  const float* W1 = (const float*)d_in[3],  *b1 = (const float*)d_in[4];
  const float* W2 = (const float*)d_in[5],  *b2 = (const float*)d_in[6];
  const float* W3 = (const float*)d_in[7],  *b3 = (const float*)d_in[8];
  const float* W4 = (const float*)d_in[9],  *b4 = (const float*)d_in[10];
  const float* W5 = (const float*)d_in[11], *b5 = (const float*)d_in[12];
  const float* W6 = (const float*)d_in[13], *b6 = (const float*)d_in[14];
  const float* fcW1 = (const float*)d_in[15], *fcb1 = (const float*)d_in[16];
  const float* fcW2 = (const float*)d_in[17], *fcb2 = (const float*)d_in[18];
  const float* fcW3 = (const float*)d_in[19], *fcb3 = (const float*)d_in[20];
  float* out = (float*)d_out;

  char* ws = (char*)d_ws;
  unsigned short* X   = (unsigned short*)(ws + OX);
  unsigned short* H   = (unsigned short*)(ws + OH);
  unsigned short* X5  = (unsigned short*)(ws + OX5);
  float* H6   = (float*)(ws + OH6);
  float* XF   = (float*)(ws + OXF);
  float* FC1o = (float*)(ws + OFC1);
  float* FC2o = (float*)(ws + OFC2);
  float* PART = (float*)(ws + OH);   // H buffer is free once the FC head starts
  unsigned short* W2T = (unsigned short*)(ws + OW2T);
  unsigned short* W3T = (unsigned short*)(ws + OW3T);
  unsigned short* W4T = (unsigned short*)(ws + OW4T);
  unsigned short* W5T = (unsigned short*)(ws + OW5T);
  float* IMG  = (float*)(ws + OIMG);
  int*   DEG  = (int*)(ws + ODEG);
  int*   CNT  = (int*)(ws + OCNT);
  int*   ROW  = (int*)(ws + OROW);
  int*   COL  = (int*)(ws + OCOL);
  float* VAL  = (float*)(ws + OVAL);
  float* SELF = (float*)(ws + OSELF);
  float* DINV = (float*)(ws + ODINV);

  // CSR build
  hipMemsetAsync(ws + ODEG, 0, OCNT - ODEG + AL((size_t)V_ * 4), stream);
  k_deg<<<(E_ + 255) / 256, 256, 0, stream>>>(ei, DEG);
  k_scan<<<1, 64, 0, stream>>>(DEG, ROW, DINV, SELF);
  k_scatter<<<(E_ + 255) / 256, 256, 0, stream>>>(ei, ROW, CNT, COL, VAL, DINV);

  // weight transposes (bf16)
  k_wt<<<(512 * 512 + 255) / 256, 256, 0, stream>>>(W2, W2T, 512, 512);
  k_wt<<<(512 * 512 + 255) / 256, 256, 0, stream>>>(W3, W3T, 512, 512);
  k_wt<<<(512 * 512 + 255) / 256, 256, 0, stream>>>(W4, W4T, 512, 512);
  k_wt<<<(512 * 64  + 255) / 256, 256, 0, stream>>>(W5, W5T, 512, 64);

  // layer 1 (fused transform + agg)
  k_imgw<<<(B_ * 512) / 256, 256, 0, stream>>>(img, W1, IMG);
  k_layer1<<<M_, 256, 0, stream>>>(vert, W1, b1, IMG, ROW, COL, VAL, SELF, X);

  // layers 2-4: GEMM 512x512 + agg (relu after 2 and 4)
  k_gemm<128,128,2,2,4,4><<<dim3(M_ / 128, 4), 256, 0, stream>>>(X, W2T, H, 512, 512);
  k_agg<512,256><<<M_, 256, 0, stream>>>(H, b2, ROW, COL, VAL, SELF, X, 1);
  k_gemm<128,128,2,2,4,4><<<dim3(M_ / 128, 4), 256, 0, stream>>>(X, W3T, H, 512, 512);
  k_agg<512,256><<<M_, 256, 0, stream>>>(H, b3, ROW, COL, VAL, SELF, X, 0);
  k_gemm<128,128,2,2,4,4><<<dim3(M_ / 128, 4), 256, 0, stream>>>(X, W4T, H, 512, 512);
  k_agg<512,256><<<M_, 256, 0, stream>>>(H, b4, ROW, COL, VAL, SELF, X, 1);

  // layer 5: GEMM 512->64 + agg
  k_gemm<128,64,4,1,2,4><<<dim3(M_ / 128, 1), 256, 0, stream>>>(X, W5T, H, 512, 64);
  k_agg<64,64><<<M_, 64, 0, stream>>>(H, b5, ROW, COL, VAL, SELF, X5, 0);

  // layer 6: 64->3 + agg + relu
  k_l6<<<M_ / 256, 256, 0, stream>>>(X5, W6, H6);
  k_agg6<<<M_ / 256, 256, 0, stream>>>(H6, b6, ROW, COL, VAL, SELF, XF);

  // FC head: split-K (stage A) + reduce (stage B). Partials in H (free now).
  // FC1: [32,6144] @ [6144,1024], KS = 6144/64 = 96
  k_fcp<64><<<dim3(1024 / 256, 6144 / 64), 256, 0, stream>>>(XF, fcW1, PART, 6144, 1024);
  k_fcr<<<(B_ * 1024) / 256, 256, 0, stream>>>(PART, fcb1, FC1o, 1024, 96, 0, nullptr);
  // FC2: [32,1024] @ [1024,1024], KS = 16
  k_fcp<64><<<dim3(1024 / 256, 1024 / 64), 256, 0, stream>>>(FC1o, fcW2, PART, 1024, 1024);
  k_fcr<<<(B_ * 1024) / 256, 256, 0, stream>>>(PART, fcb2, FC2o, 1024, 16, 0, nullptr);
  // FC3: [32,1024] @ [1024,6144], KS = 16, fused vert + 0.1*tanh
  k_fcp<64><<<dim3(6144 / 256, 1024 / 64), 256, 0, stream>>>(FC2o, fcW3, PART, 1024, 6144);
  k_fcr<<<(B_ * 6144) / 256, 256, 0, stream>>>(PART, fcb3, out, 6144, 16, 1, vert);
}

// Round 3
// 846.409 us; speedup vs baseline: 2.0233x; 1.1259x over previous
//
#include <hip/hip_runtime.h>
#include <stdint.h>
#include <math.h>

#define B_ 32
#define V_ 2048
#define E_ 12288
#define M_ (B_*V_)

typedef __bf16 bf16x8 __attribute__((ext_vector_type(8)));
typedef float f32x4 __attribute__((ext_vector_type(4)));

__device__ __forceinline__ float bf2f(unsigned short u){
  union { unsigned int i; float f; } v; v.i = ((unsigned int)u) << 16; return v.f;
}
__device__ __forceinline__ unsigned short f2bf(float f){
  union { float f; unsigned int i; } v; v.f = f;
  unsigned int r = (v.i + 0x7fffu + ((v.i >> 16) & 1u)) >> 16;
  return (unsigned short)r;
}

// ---------------- CSR build ----------------
__global__ void k_deg(const int* __restrict__ ei, int* __restrict__ deg){
  int e = blockIdx.x * 256 + threadIdx.x;
  if (e < E_) atomicAdd(&deg[ei[E_ + e]], 1);   // dst side
}

__global__ void k_scan(const int* __restrict__ cnt, int* __restrict__ rowptr,
                       float* __restrict__ dinv, float* __restrict__ selfw){
  int lane = threadIdx.x;      // 64 threads
  int base = lane * 32;
  int local[32]; int s = 0;
  #pragma unroll
  for (int i = 0; i < 32; i++){ local[i] = cnt[base + i]; s += local[i]; }
  int pre = s;
  for (int off = 1; off < 64; off <<= 1){
    int t = __shfl_up(pre, off);
    if (lane >= off) pre += t;
  }
  pre -= s;  // exclusive
  int run = pre;
  #pragma unroll
  for (int i = 0; i < 32; i++){
    rowptr[base + i] = run; run += local[i];
    float d = (float)(local[i] + 1);          // + self loop
    float di = rsqrtf(d);
    dinv[base + i] = di;
    selfw[base + i] = di * di;
  }
  if (lane == 63) rowptr[V_] = run;
}

__global__ void k_scatter(const int* __restrict__ ei, const int* __restrict__ rowptr,
                          int* __restrict__ fill, int* __restrict__ cols,
                          float* __restrict__ vals, const float* __restrict__ dinv){
  int e = blockIdx.x * 256 + threadIdx.x;
  if (e < E_){
    int s = ei[e], d = ei[E_ + e];
    int pos = rowptr[d] + atomicAdd(&fill[d], 1);
    cols[pos] = s;
    vals[pos] = dinv[s] * dinv[d];
  }
}

__global__ void k_wsum(const int* __restrict__ rowptr, const float* __restrict__ vals,
                       const float* __restrict__ selfw, float* __restrict__ wsum){
  int v = blockIdx.x * 256 + threadIdx.x;
  if (v < V_){
    float s = selfw[v];
    for (int e = rowptr[v]; e < rowptr[v + 1]; e++) s += vals[e];
    wsum[v] = s;
  }
}

__global__ void k_w2(const int* __restrict__ rowptr, const int* __restrict__ cols,
                     const float* __restrict__ vals, const float* __restrict__ selfw,
                     const float* __restrict__ wsum, float* __restrict__ w2){
  int v = blockIdx.x * 256 + threadIdx.x;
  if (v < V_){
    float s = selfw[v] * wsum[v];
    for (int e = rowptr[v]; e < rowptr[v + 1]; e++) s += vals[e] * wsum[cols[e]];
    w2[v] = s;
  }
}

// ---------------- weight converts ----------------
// Wt[n*K+k] = bf16(W[k*N+n])  (transpose)
__global__ void k_wt(const float* __restrict__ W, unsigned short* __restrict__ Wt,
                     int K, int N){
  int id = blockIdx.x * 256 + threadIdx.x;
  if (id < K * N){
    int n = id / K, k = id % K;
    Wt[id] = f2bf(W[(size_t)k * N + n]);
  }
}
// plain convert
__global__ void k_cvt(const float* __restrict__ W, unsigned short* __restrict__ Wb, int n){
  int id = blockIdx.x * 256 + threadIdx.x;
  if (id < n) Wb[id] = f2bf(W[id]);
}

// ---------------- small fp32 vec-mat: out[r,n] = sum_k in[r*K+k] * W[k*N+n] ----------------
__global__ void k_vm(const float* __restrict__ in, const float* __restrict__ W,
                     float* __restrict__ out, int R, int K, int N){
  int id = blockIdx.x * 256 + threadIdx.x;
  if (id >= R * N) return;
  int r = id / N, n = id % N;
  const float* x = in + (size_t)r * K;
  const float* w = W + n;
  float acc = 0.f;
  for (int k = 0; k < K; k += 4){
    acc += x[k]     * w[(size_t)k * N]
         + x[k + 1] * w[(size_t)(k + 1) * N]
         + x[k + 2] * w[(size_t)(k + 2) * N]
         + x[k + 3] * w[(size_t)(k + 3) * N];
  }
  out[id] = acc;
}

// ---------------- F=3 fp32 aggregation (thread per b*V+dst) ----------------
__global__ void k_agg3f(const float* __restrict__ h, const int* __restrict__ rowptr,
                        const int* __restrict__ cols, const float* __restrict__ vals,
                        const float* __restrict__ selfw, float* __restrict__ out,
                        const float* __restrict__ cvec, const float* __restrict__ bias,
                        int relu){
  int id = blockIdx.x * 256 + threadIdx.x;   // m = b*V + dst
  int dst = id & (V_ - 1);
  const float* hb = h + (size_t)(id - dst) * 3;   // batch base
  float sw = selfw[dst];
  float a0 = sw * hb[dst * 3], a1 = sw * hb[dst * 3 + 1], a2 = sw * hb[dst * 3 + 2];
  float wsum = sw;
  int rs = rowptr[dst], re = rowptr[dst + 1];
  for (int e = rs; e < re; e++){
    int s = cols[e]; float vv = vals[e]; wsum += vv;
    a0 += vv * hb[s * 3]; a1 += vv * hb[s * 3 + 1]; a2 += vv * hb[s * 3 + 2];
  }
  if (cvec){
    a0 += wsum * cvec[0] + bias[0];
    a1 += wsum * cvec[1] + bias[1];
    a2 += wsum * cvec[2] + bias[2];
  }
  if (relu){ a0 = fmaxf(a0, 0.f); a1 = fmaxf(a1, 0.f); a2 = fmaxf(a2, 0.f); }
  out[(size_t)id * 3] = a0; out[(size_t)id * 3 + 1] = a1; out[(size_t)id * 3 + 2] = a2;
}

// ---------------- x2 build: relu(VA2*Wv + w2*i12 + wsum*c12 + b2) -> bf16 ----------------
__global__ __launch_bounds__(256) void k_x2(
    const float* __restrict__ va2, const float* __restrict__ wv,
    const float* __restrict__ i12, const float* __restrict__ wsum,
    const float* __restrict__ w2s, const float* __restrict__ c12,
    const float* __restrict__ b2, unsigned short* __restrict__ X){
  int m = blockIdx.x;               // b*V + v
  int b = m >> 11, v = m & (V_ - 1);
  int t = threadIdx.x, f = t * 2;
  float x0 = va2[(size_t)m * 3], x1 = va2[(size_t)m * 3 + 1], x2v = va2[(size_t)m * 3 + 2];
  float ws = wsum[v], w2 = w2s[v];
  float r0 = x0 * wv[f]     + x1 * wv[512 + f]     + x2v * wv[1024 + f]
           + w2 * i12[b * 512 + f]     + ws * c12[f]     + b2[f];
  float r1 = x0 * wv[f + 1] + x1 * wv[512 + f + 1] + x2v * wv[1024 + f + 1]
           + w2 * i12[b * 512 + f + 1] + ws * c12[f + 1] + b2[f + 1];
  r0 = fmaxf(r0, 0.f); r1 = fmaxf(r1, 0.f);
  ((unsigned int*)X)[(size_t)m * 256 + t] =
      (unsigned int)f2bf(r0) | ((unsigned int)f2bf(r1) << 16);
}

// ---------------- F=512 bf16 aggregation, batched for MLP ----------------
// block = (dst, group of BGRP batches); 256 threads over 512 features (pairs).
// Per edge: BGRP independent 1KB row loads in flight -> latency hidden.
template<int BGRP>
__global__ __launch_bounds__(256) void k_aggb(
    const unsigned short* __restrict__ Hg, const int* __restrict__ rowptr,
    const int* __restrict__ cols, const float* __restrict__ vals,
    const float* __restrict__ selfw, unsigned short* __restrict__ Xo){
  int dst = blockIdx.x;
  int b0 = blockIdx.y * BGRP;
  int tid = threadIdx.x;
  float sw = selfw[dst];
  int rs = rowptr[dst], re = rowptr[dst + 1];
  const unsigned int* base = (const unsigned int*)Hg;   // packed pairs, row stride 256
  float a0[BGRP], a1[BGRP];
  #pragma unroll
  for (int j = 0; j < BGRP; j++){
    unsigned int u = base[((size_t)(b0 + j) * V_ + dst) * 256 + tid];
    a0[j] = sw * bf2f(u & 0xffff); a1[j] = sw * bf2f(u >> 16);
  }
  for (int e = rs; e < re; e++){
    int s = cols[e]; float v = vals[e];
    unsigned int u[BGRP];
    #pragma unroll
    for (int j = 0; j < BGRP; j++)
      u[j] = base[((size_t)(b0 + j) * V_ + s) * 256 + tid];
    #pragma unroll
    for (int j = 0; j < BGRP; j++){
      a0[j] += v * bf2f(u[j] & 0xffff); a1[j] += v * bf2f(u[j] >> 16);
    }
  }
  #pragma unroll
  for (int j = 0; j < BGRP; j++){
    ((unsigned int*)Xo)[((size_t)(b0 + j) * V_ + dst) * 256 + tid] =
        (unsigned int)f2bf(a0[j]) | ((unsigned int)f2bf(a1[j]) << 16);
  }
}

// ---------------- bf16 MFMA GEMM: Hg[M,N] = Xg[M,K] @ Wt^T, optional fused epilogue ----------------
// epilogue (cvec != null): x += wsumv[row & (V-1)]*cvec[col] + bias[col]; relu optional.
template<int BM, int BN, int WM, int WN, int TM, int TN>
__global__ __launch_bounds__(WM*WN*64) void k_gemm(
    const unsigned short* __restrict__ Xg, const unsigned short* __restrict__ Wt,
    unsigned short* __restrict__ Hg, int K, int N,
    const float* __restrict__ wsumv, const float* __restrict__ cvec,
    const float* __restrict__ bias, int relu){
  constexpr int BK = 32;
  constexpr int LDA = BK + 8;
  __shared__ __align__(16) unsigned short As[BM * LDA];
  __shared__ __align__(16) unsigned short Bs[BN * LDA];
  const int tid = threadIdx.x;
  const int row0 = blockIdx.x * BM, col0 = blockIdx.y * BN;
  const int wave = tid >> 6, lane = tid & 63;
  const int wr = wave / WN, wc = wave % WN;
  const int lrow = lane & 15, lq = lane >> 4;
  f32x4 acc[TM][TN] = {};
  constexpr int NT  = WM * WN * 64;
  constexpr int NCA = (BM * 4) / NT;
  constexpr int NCB = (BN * 4) / NT;
  for (int k0 = 0; k0 < K; k0 += BK){
    __syncthreads();
    #pragma unroll
    for (int i = 0; i < NCA; i++){
      int c = tid + i * NT;
      int m = c >> 2, kk = (c & 3) << 3;
      *(uint4*)&As[m * LDA + kk] = *(const uint4*)&Xg[(size_t)(row0 + m) * K + k0 + kk];
    }
    #pragma unroll
    for (int i = 0; i < NCB; i++){
      int c = tid + i * NT;
      int n = c >> 2, kk = (c & 3) << 3;
      *(uint4*)&Bs[n * LDA + kk] = *(const uint4*)&Wt[(size_t)(col0 + n) * K + k0 + kk];
    }
    __syncthreads();
    bf16x8 af[TM], bfr[TN];
    #pragma unroll
    for (int tm = 0; tm < TM; tm++)
      af[tm] = *(const bf16x8*)&As[(wr * TM * 16 + tm * 16 + lrow) * LDA + lq * 8];
    #pragma unroll
    for (int tn = 0; tn < TN; tn++)
      bfr[tn] = *(const bf16x8*)&Bs[(wc * TN * 16 + tn * 16 + lrow) * LDA + lq * 8];
    #pragma unroll
    for (int tm = 0; tm < TM; tm++)
      #pragma unroll
      for (int tn = 0; tn < TN; tn++)
        acc[tm][tn] = __builtin_amdgcn_mfma_f32_16x16x32_bf16(af[tm], bfr[tn], acc[tm][tn], 0, 0, 0);
  }
  #pragma unroll
  for (int tm = 0; tm < TM; tm++){
    #pragma unroll
    for (int tn = 0; tn < TN; tn++){
      int col = col0 + wc * TN * 16 + tn * 16 + lrow;
      float cv = 0.f, bv = 0.f;
      if (cvec){ cv = cvec[col]; bv = bias[col]; }
      #pragma unroll
      for (int r = 0; r < 4; r++){
        int row = row0 + wr * TM * 16 + tm * 16 + lq * 4 + r;
        float x = acc[tm][tn][r];
        if (cvec) x += wsumv[row & (V_ - 1)] * cv + bv;
        if (relu) x = fmaxf(x, 0.f);
        Hg[(size_t)row * N + col] = f2bf(x);
      }
    }
  }
}

// ---------------- h5 = x4 @ W56  (K=512, N=3, fp32 out) ----------------
__global__ void k_h5(const unsigned short* __restrict__ x4, const float* __restrict__ W56,
                     float* __restrict__ h5){
  int m = blockIdx.x * 256 + threadIdx.x;
  const unsigned short* xr = x4 + (size_t)m * 512;
  float a0 = 0.f, a1 = 0.f, a2 = 0.f;
  for (int k = 0; k < 512; k += 8){
    uint4 q = *(const uint4*)&xr[k];
    const unsigned short* p = (const unsigned short*)&q;
    #pragma unroll
    for (int j = 0; j < 8; j++){
      float x = bf2f(p[j]);
      a0 += x * W56[(k + j) * 3 + 0];
      a1 += x * W56[(k + j) * 3 + 1];
      a2 += x * W56[(k + j) * 3 + 2];
    }
  }
  h5[(size_t)m * 3 + 0] = a0; h5[(size_t)m * 3 + 1] = a1; h5[(size_t)m * 3 + 2] = a2;
}

// ---------------- FC split-K stage A ----------------
template<int KC>
__global__ __launch_bounds__(256) void k_fcp(
    const float* __restrict__ in, const float* __restrict__ W,
    float* __restrict__ partial, int K, int N){
  const int n = blockIdx.x * 256 + threadIdx.x;
  const int k0 = blockIdx.y * KC;
  float acc[B_] = {};
  for (int kk = 0; kk < KC; kk += 4){
    const float* wp = W + (size_t)(k0 + kk) * N + n;
    float w0 = wp[0];
    float w1 = wp[(size_t)N];
    float w2 = wp[(size_t)2 * N];
    float w3 = wp[(size_t)3 * N];
    #pragma unroll
    for (int b = 0; b < B_; b++){
      const float* xp = in + (size_t)b * K + k0 + kk;
      acc[b] += xp[0] * w0 + xp[1] * w1 + xp[2] * w2 + xp[3] * w3;
    }
  }
  float* p = partial + (size_t)blockIdx.y * B_ * N + n;
  #pragma unroll
  for (int b = 0; b < B_; b++) p[(size_t)b * N] = acc[b];
}

// ---------------- FC split-K stage B ----------------
__global__ __launch_bounds__(256) void k_fcr(
    const float* __restrict__ partial, const float* __restrict__ bias,
    float* __restrict__ out, int N, int KS, int mode, const float* __restrict__ vert){
  int id = blockIdx.x * 256 + threadIdx.x;   // B_*N threads
  int n = id % N;
  float acc = bias[n];
  for (int s = 0; s < KS; s++) acc += partial[(size_t)s * B_ * N + id];
  if (mode) acc = vert[id] + 0.1f * tanhf(acc);
  out[id] = acc;
}

// ---------------- workspace layout ----------------
static constexpr size_t AL(size_t x){ return (x + 255) & ~(size_t)255; }
static constexpr size_t S512 = (size_t)M_ * 512 * 2;   // 64 MiB bf16 buffer
static constexpr size_t S3   = (size_t)M_ * 3 * 4;
static constexpr size_t OXA  = 0;
static constexpr size_t OXB  = OXA  + AL(S512);
static constexpr size_t OVA1 = OXB  + AL(S512);
static constexpr size_t OVA2 = OVA1 + AL(S3);
static constexpr size_t OH5  = OVA2 + AL(S3);
static constexpr size_t OH6  = OH5  + AL(S3);
static constexpr size_t OXF  = OH6  + AL(S3);
static constexpr size_t OFC1 = OXF  + AL(S3);
static constexpr size_t OFC2 = OFC1 + AL((size_t)B_ * 1024 * 4);
static constexpr size_t OI1  = OFC2 + AL((size_t)B_ * 1024 * 4);
static constexpr size_t OI12 = OI1  + AL((size_t)B_ * 512 * 4);
static constexpr size_t OWV  = OI12 + AL((size_t)B_ * 512 * 4);
static constexpr size_t OC12 = OWV  + AL((size_t)3 * 512 * 4);
static constexpr size_t OC34 = OC12 + AL((size_t)512 * 4);
static constexpr size_t OW56 = OC34 + AL((size_t)512 * 4);
static constexpr size_t OC56 = OW56 + AL((size_t)512 * 3 * 4);
static constexpr size_t OWS  = OC56 + AL((size_t)3 * 4);
static constexpr size_t OW2S = OWS  + AL((size_t)V_ * 4);
static constexpr size_t OW3B = OW2S + AL((size_t)V_ * 4);
static constexpr size_t OW4T = OW3B + AL((size_t)512 * 512 * 2);
static constexpr size_t OW34 = OW4T + AL((size_t)512 * 512 * 2);
static constexpr size_t ODEG = OW34 + AL((size_t)512 * 512 * 2);
static constexpr size_t OCNT = ODEG + AL((size_t)V_ * 4);
static constexpr size_t OROW = OCNT + AL((size_t)V_ * 4);
static constexpr size_t OCOL = OROW + AL((size_t)(V_ + 1) * 4);
static constexpr size_t OVAL = OCOL + AL((size_t)E_ * 4);
static constexpr size_t OSELF= OVAL + AL((size_t)E_ * 4);
static constexpr size_t ODINV= OSELF+ AL((size_t)V_ * 4);

extern "C" void kernel_launch(void* const* d_in, const int* in_sizes, int n_in,
                              void* d_out, int out_size, void* d_ws, size_t ws_size,
                              hipStream_t stream){
  const float* vert  = (const float*)d_in[0];
  const float* img   = (const float*)d_in[1];
  const int*   ei    = (const int*)  d_in[2];
  const float* W1 = (const float*)d_in[3],  *b1 = (const float*)d_in[4];
  const float* W2 = (const float*)d_in[5],  *b2 = (const float*)d_in[6];
  const float* W3 = (const float*)d_in[7],  *b3 = (const float*)d_in[8];
  const float* W4 = (const float*)d_in[9],  *b4 = (const float*)d_in[10];
  const float* W5 = (const float*)d_in[11], *b5 = (const float*)d_in[12];
  const float* W6 = (const float*)d_in[13], *b6 = (const float*)d_in[14];
  const float* fcW1 = (const float*)d_in[15], *fcb1 = (const float*)d_in[16];
  const float* fcW2 = (const float*)d_in[17], *fcb2 = (const float*)d_in[18];
  const float* fcW3 = (const float*)d_in[19], *fcb3 = (const float*)d_in[20];
  float* out = (float*)d_out;

  char* ws = (char*)d_ws;
  unsigned short* XA  = (unsigned short*)(ws + OXA);
  unsigned short* XB  = (unsigned short*)(ws + OXB);
  float* VA1  = (float*)(ws + OVA1);
  float* VA2  = (float*)(ws + OVA2);
  float* H5   = (float*)(ws + OH5);
  float* H6   = (float*)(ws + OH6);
  float* XF   = (float*)(ws + OXF);
  float* FC1o = (float*)(ws + OFC1);
  float* FC2o = (float*)(ws + OFC2);
  float* I1   = (float*)(ws + OI1);
  float* I12  = (float*)(ws + OI12);
  float* WV   = (float*)(ws + OWV);
  float* C12  = (float*)(ws + OC12);
  float* C34  = (float*)(ws + OC34);
  float* W56  = (float*)(ws + OW56);
  float* C56  = (float*)(ws + OC56);
  float* WSUM = (float*)(ws + OWS);
  float* W2S  = (float*)(ws + OW2S);
  unsigned short* W3B = (unsigned short*)(ws + OW3B);
  unsigned short* W4T = (unsigned short*)(ws + OW4T);
  unsigned short* W34 = (unsigned short*)(ws + OW34);
  float* PART = (float*)(ws + OXA);    // reuse XA after big GEMM
  int*   DEG  = (int*)(ws + ODEG);
  int*   CNT  = (int*)(ws + OCNT);
  int*   ROW  = (int*)(ws + OROW);
  int*   COL  = (int*)(ws + OCOL);
  float* VAL  = (float*)(ws + OVAL);
  float* SELF = (float*)(ws + OSELF);
  float* DINV = (float*)(ws + ODINV);

  // ---- CSR + norm powers ----
  hipMemsetAsync(ws + ODEG, 0, OROW - ODEG, stream);
  k_deg<<<(E_ + 255) / 256, 256, 0, stream>>>(ei, DEG);
  k_scan<<<1, 64, 0, stream>>>(DEG, ROW, DINV, SELF);
  k_scatter<<<(E_ + 255) / 256, 256, 0, stream>>>(ei, ROW, CNT, COL, VAL, DINV);
  k_wsum<<<(V_ + 255) / 256, 256, 0, stream>>>(ROW, VAL, SELF, WSUM);
  k_w2<<<(V_ + 255) / 256, 256, 0, stream>>>(ROW, COL, VAL, SELF, WSUM, W2S);

  // ---- weight precompute ----
  k_cvt<<<(512 * 512 + 255) / 256, 256, 0, stream>>>(W3, W3B, 512 * 512);
  k_wt<<<(512 * 512 + 255) / 256, 256, 0, stream>>>(W4, W4T, 512, 512);
  // W34T = (W3*W4)^T via MFMA: out[n, k3] = sum_k W4T[n,k] * W3[k3,k]
  k_gemm<128,128,2,2,4,4><<<dim3(4, 4), 256, 0, stream>>>(W4T, W3B, W34, 512, 512,
                                                          nullptr, nullptr, nullptr, 0);
  k_vm<<<(32 * 512 + 255) / 256, 256, 0, stream>>>(img, W1 + 3 * 512, I1, 32, 512, 512);
  k_vm<<<(32 * 512 + 255) / 256, 256, 0, stream>>>(I1, W2, I12, 32, 512, 512);
  k_vm<<<(512 + 255) / 256, 256, 0, stream>>>(b1, W2, C12, 1, 512, 512);
  k_vm<<<(3 * 512 + 255) / 256, 256, 0, stream>>>(W1, W2, WV, 3, 512, 512);
  k_vm<<<(512 + 255) / 256, 256, 0, stream>>>(b3, W4, C34, 1, 512, 512);
  k_vm<<<(512 * 3 + 255) / 256, 256, 0, stream>>>(W5, W6, W56, 512, 64, 3);
  k_vm<<<(3 + 255) / 256, 256, 0, stream>>>(b5, W6, C56, 1, 64, 3);

  // ---- layers 1+2: x2 = relu((A^2 vert)Wv + w2*i12 + wsum*c12 + b2) ----
  k_agg3f<<<M_ / 256, 256, 0, stream>>>(vert, ROW, COL, VAL, SELF, VA1, nullptr, nullptr, 0);
  k_agg3f<<<M_ / 256, 256, 0, stream>>>(VA1, ROW, COL, VAL, SELF, VA2, nullptr, nullptr, 0);
  k_x2<<<M_, 256, 0, stream>>>(VA2, WV, I12, WSUM, W2S, C12, b2, XA);

  // ---- layers 3+4: x4 = relu((A^2 x2) W34 + wsum*c34 + b4) ----
  k_aggb<16><<<dim3(V_, 2), 256, 0, stream>>>(XA, ROW, COL, VAL, SELF, XB);
  k_aggb<16><<<dim3(V_, 2), 256, 0, stream>>>(XB, ROW, COL, VAL, SELF, XA);
  k_gemm<128,128,2,2,4,4><<<dim3(M_ / 128, 4), 256, 0, stream>>>(XA, W34, XB, 512, 512,
                                                                 WSUM, C34, b4, 1);

  // ---- layers 5+6: x6 = relu(A^2 (x4 W56) + wsum*c56 + b6) ----
  k_h5<<<M_ / 256, 256, 0, stream>>>(XB, W56, H5);
  k_agg3f<<<M_ / 256, 256, 0, stream>>>(H5, ROW, COL, VAL, SELF, H6, nullptr, nullptr, 0);
  k_agg3f<<<M_ / 256, 256, 0, stream>>>(H6, ROW, COL, VAL, SELF, XF, C56, b6, 1);

  // ---- FC head ----
  k_fcp<64><<<dim3(1024 / 256, 6144 / 64), 256, 0, stream>>>(XF, fcW1, PART, 6144, 1024);
  k_fcr<<<(B_ * 1024) / 256, 256, 0, stream>>>(PART, fcb1, FC1o, 1024, 96, 0, nullptr);
  k_fcp<64><<<dim3(1024 / 256, 1024 / 64), 256, 0, stream>>>(FC1o, fcW2, PART, 1024, 1024);
  k_fcr<<<(B_ * 1024) / 256, 256, 0, stream>>>(PART, fcb2, FC2o, 1024, 16, 0, nullptr);
  k_fcp<64><<<dim3(6144 / 256, 1024 / 64), 256, 0, stream>>>(FC2o, fcW3, PART, 1024, 6144);
  k_fcr<<<(B_ * 6144) / 256, 256, 0, stream>>>(PART, fcb3, out, 6144, 16, 1, vert);
}

// Round 4
// 723.601 us; speedup vs baseline: 2.3667x; 1.1697x over previous
//
#include <hip/hip_runtime.h>
#include <stdint.h>
#include <math.h>

#define B_ 32
#define V_ 2048
#define E_ 12288
#define M_ (B_*V_)

typedef __bf16 bf16x8 __attribute__((ext_vector_type(8)));
typedef float f32x4 __attribute__((ext_vector_type(4)));

__device__ __forceinline__ float bf2f(unsigned short u){
  union { unsigned int i; float f; } v; v.i = ((unsigned int)u) << 16; return v.f;
}
__device__ __forceinline__ unsigned short f2bf(float f){
  union { float f; unsigned int i; } v; v.f = f;
  unsigned int r = (v.i + 0x7fffu + ((v.i >> 16) & 1u)) >> 16;
  return (unsigned short)r;
}
// async global->LDS, 16B per lane; LDS dest = uniform base + lane*16
__device__ __forceinline__ void gload16(const unsigned short* g, unsigned short* l){
  __builtin_amdgcn_global_load_lds(
      (const __attribute__((address_space(1))) void*)g,
      (__attribute__((address_space(3))) void*)l, 16, 0, 0);
}

// ---------------- CSR build ----------------
__global__ void k_deg(const int* __restrict__ ei, int* __restrict__ deg){
  int e = blockIdx.x * 256 + threadIdx.x;
  if (e < E_) atomicAdd(&deg[ei[E_ + e]], 1);   // dst side
}

__global__ void k_scan(const int* __restrict__ cnt, int* __restrict__ rowptr,
                       float* __restrict__ dinv, float* __restrict__ selfw){
  int lane = threadIdx.x;      // 64 threads
  int base = lane * 32;
  int local[32]; int s = 0;
  #pragma unroll
  for (int i = 0; i < 32; i++){ local[i] = cnt[base + i]; s += local[i]; }
  int pre = s;
  for (int off = 1; off < 64; off <<= 1){
    int t = __shfl_up(pre, off);
    if (lane >= off) pre += t;
  }
  pre -= s;  // exclusive
  int run = pre;
  #pragma unroll
  for (int i = 0; i < 32; i++){
    rowptr[base + i] = run; run += local[i];
    float d = (float)(local[i] + 1);          // + self loop
    float di = rsqrtf(d);
    dinv[base + i] = di;
    selfw[base + i] = di * di;
  }
  if (lane == 63) rowptr[V_] = run;
}

__global__ void k_scatter(const int* __restrict__ ei, const int* __restrict__ rowptr,
                          int* __restrict__ fill, int* __restrict__ cols,
                          float* __restrict__ vals, const float* __restrict__ dinv){
  int e = blockIdx.x * 256 + threadIdx.x;
  if (e < E_){
    int s = ei[e], d = ei[E_ + e];
    int pos = rowptr[d] + atomicAdd(&fill[d], 1);
    cols[pos] = s;
    vals[pos] = dinv[s] * dinv[d];
  }
}

__global__ void k_wsum(const int* __restrict__ rowptr, const float* __restrict__ vals,
                       const float* __restrict__ selfw, float* __restrict__ wsum){
  int v = blockIdx.x * 256 + threadIdx.x;
  if (v < V_){
    float s = selfw[v];
    for (int e = rowptr[v]; e < rowptr[v + 1]; e++) s += vals[e];
    wsum[v] = s;
  }
}

__global__ void k_w2(const int* __restrict__ rowptr, const int* __restrict__ cols,
                     const float* __restrict__ vals, const float* __restrict__ selfw,
                     const float* __restrict__ wsum, float* __restrict__ w2){
  int v = blockIdx.x * 256 + threadIdx.x;
  if (v < V_){
    float s = selfw[v] * wsum[v];
    for (int e = rowptr[v]; e < rowptr[v + 1]; e++) s += vals[e] * wsum[cols[e]];
    w2[v] = s;
  }
}

// ---------------- weight converts ----------------
__global__ void k_wt(const float* __restrict__ W, unsigned short* __restrict__ Wt,
                     int K, int N){
  int id = blockIdx.x * 256 + threadIdx.x;
  if (id < K * N){
    int n = id / K, k = id % K;
    Wt[id] = f2bf(W[(size_t)k * N + n]);
  }
}
__global__ void k_cvt(const float* __restrict__ W, unsigned short* __restrict__ Wb, int n){
  int id = blockIdx.x * 256 + threadIdx.x;
  if (id < n) Wb[id] = f2bf(W[id]);
}

// ---------------- small fp32 vec-mat (tiny shapes only) ----------------
__global__ void k_vm(const float* __restrict__ in, const float* __restrict__ W,
                     float* __restrict__ out, int R, int K, int N){
  int id = blockIdx.x * 256 + threadIdx.x;
  if (id >= R * N) return;
  int r = id / N, n = id % N;
  const float* x = in + (size_t)r * K;
  const float* w = W + n;
  float acc = 0.f;
  for (int k = 0; k < K; k += 4){
    acc += x[k]     * w[(size_t)k * N]
         + x[k + 1] * w[(size_t)(k + 1) * N]
         + x[k + 2] * w[(size_t)(k + 2) * N]
         + x[k + 3] * w[(size_t)(k + 3) * N];
  }
  out[id] = acc;
}

// ---------------- split-K stage A: partial[s][r][n], R rows resident in regs ----------------
template<int R, int KC>
__global__ __launch_bounds__(256) void k_fcp(
    const float* __restrict__ in, const float* __restrict__ W,
    float* __restrict__ partial, int K, int N){
  const int n = blockIdx.x * 256 + threadIdx.x;
  const int k0 = blockIdx.y * KC;
  float acc[R] = {};
  for (int kk = 0; kk < KC; kk += 4){
    const float* wp = W + (size_t)(k0 + kk) * N + n;
    float w0 = wp[0];
    float w1 = wp[(size_t)N];
    float w2 = wp[(size_t)2 * N];
    float w3 = wp[(size_t)3 * N];
    #pragma unroll
    for (int r = 0; r < R; r++){
      const float* xp = in + (size_t)r * K + k0 + kk;
      acc[r] += xp[0] * w0 + xp[1] * w1 + xp[2] * w2 + xp[3] * w3;
    }
  }
  float* p = partial + (size_t)blockIdx.y * R * N + n;
  #pragma unroll
  for (int r = 0; r < R; r++) p[(size_t)r * N] = acc[r];
}

// ---------------- split-K stage B: out[id] = sum_s partial[s][id] (+bias) (+vert+0.1*tanh) ----------------
__global__ __launch_bounds__(256) void k_fcr(
    const float* __restrict__ partial, const float* __restrict__ bias,
    float* __restrict__ out, int total, int N, int KS, int mode,
    const float* __restrict__ vert){
  int id = blockIdx.x * 256 + threadIdx.x;
  if (id >= total) return;
  int n = id % N;
  float a0 = 0.f, a1 = 0.f, a2 = 0.f, a3 = 0.f;
  int s = 0;
  for (; s + 4 <= KS; s += 4){
    a0 += partial[(size_t)s * total + id];
    a1 += partial[(size_t)(s + 1) * total + id];
    a2 += partial[(size_t)(s + 2) * total + id];
    a3 += partial[(size_t)(s + 3) * total + id];
  }
  for (; s < KS; s++) a0 += partial[(size_t)s * total + id];
  float acc = a0 + a1 + a2 + a3;
  if (bias) acc += bias[n];
  if (mode) acc = vert[id] + 0.1f * tanhf(acc);
  out[id] = acc;
}

// ---------------- CAT = [b1; W1 rows 0-2; I1]  (36 x 512) ----------------
__global__ void k_cat36(const float* __restrict__ b1, const float* __restrict__ W1,
                        const float* __restrict__ I1, float* __restrict__ CAT){
  int id = blockIdx.x * 256 + threadIdx.x;
  if (id >= 36 * 512) return;
  int r = id >> 9, c = id & 511;
  float v;
  if (r == 0)      v = b1[c];
  else if (r < 4)  v = W1[(r - 1) * 512 + c];
  else             v = I1[(r - 4) * 512 + c];
  CAT[id] = v;
}

// ---------------- F=3 fp32 aggregation (thread per b*V+dst) ----------------
__global__ void k_agg3f(const float* __restrict__ h, const int* __restrict__ rowptr,
                        const int* __restrict__ cols, const float* __restrict__ vals,
                        const float* __restrict__ selfw, float* __restrict__ out,
                        const float* __restrict__ cvec, const float* __restrict__ bias,
                        int relu){
  int id = blockIdx.x * 256 + threadIdx.x;   // m = b*V + dst
  int dst = id & (V_ - 1);
  const float* hb = h + (size_t)(id - dst) * 3;   // batch base
  float sw = selfw[dst];
  float a0 = sw * hb[dst * 3], a1 = sw * hb[dst * 3 + 1], a2 = sw * hb[dst * 3 + 2];
  float wsum = sw;
  int rs = rowptr[dst], re = rowptr[dst + 1];
  for (int e = rs; e < re; e++){
    int s = cols[e]; float vv = vals[e]; wsum += vv;
    a0 += vv * hb[s * 3]; a1 += vv * hb[s * 3 + 1]; a2 += vv * hb[s * 3 + 2];
  }
  if (cvec){
    a0 += wsum * cvec[0] + bias[0];
    a1 += wsum * cvec[1] + bias[1];
    a2 += wsum * cvec[2] + bias[2];
  }
  if (relu){ a0 = fmaxf(a0, 0.f); a1 = fmaxf(a1, 0.f); a2 = fmaxf(a2, 0.f); }
  out[(size_t)id * 3] = a0; out[(size_t)id * 3 + 1] = a1; out[(size_t)id * 3 + 2] = a2;
}

// ---------------- x2 build: relu(VA2*Wv + w2*i12 + wsum*c12 + b2) -> bf16, uint4 stores ----------------
// P layout: row0 = c12 (b1@W2), rows1-3 = Wv (W1[0:3]@W2), rows4-35 = i12 (img@W1'@W2)
__global__ __launch_bounds__(256) void k_x2(
    const float* __restrict__ va2, const float* __restrict__ P,
    const float* __restrict__ wsum, const float* __restrict__ w2s,
    const float* __restrict__ b2, unsigned short* __restrict__ X){
  int m = blockIdx.x * 4 + (threadIdx.x >> 6);
  int b = m >> 11, v = m & (V_ - 1);
  int f = (threadIdx.x & 63) * 8;
  const float* c12 = P;
  const float* wv  = P + 512;
  const float* i12 = P + 4 * 512 + (size_t)b * 512;
  float x0 = va2[(size_t)m * 3], x1 = va2[(size_t)m * 3 + 1], x2v = va2[(size_t)m * 3 + 2];
  float ws = wsum[v], w2 = w2s[v];
  unsigned int o[4];
  #pragma unroll
  for (int i = 0; i < 4; i++){
    int fc = f + 2 * i;
    float r0 = x0 * wv[fc]     + x1 * wv[512 + fc]     + x2v * wv[1024 + fc]
             + w2 * i12[fc]     + ws * c12[fc]     + b2[fc];
    float r1 = x0 * wv[fc + 1] + x1 * wv[512 + fc + 1] + x2v * wv[1024 + fc + 1]
             + w2 * i12[fc + 1] + ws * c12[fc + 1] + b2[fc + 1];
    r0 = fmaxf(r0, 0.f); r1 = fmaxf(r1, 0.f);
    o[i] = (unsigned int)f2bf(r0) | ((unsigned int)f2bf(r1) << 16);
  }
  *(uint4*)&X[(size_t)m * 512 + f] = *(uint4*)o;
}

// ---------------- F=512 bf16 aggregation, uint4 gathers, 4 batches per 64-lane group ----------------
template<int BGRP>
__global__ __launch_bounds__(256) void k_aggb(
    const unsigned short* __restrict__ Hg, const int* __restrict__ rowptr,
    const int* __restrict__ cols, const float* __restrict__ vals,
    const float* __restrict__ selfw, unsigned short* __restrict__ Xo){
  constexpr int NJ = BGRP / 4;
  int dst = blockIdx.x;
  int b = blockIdx.y * BGRP + (threadIdx.x >> 6);
  int f8 = (threadIdx.x & 63) * 8;
  float sw = selfw[dst];
  int rs = rowptr[dst], re = rowptr[dst + 1];
  float a[NJ][8];
  #pragma unroll
  for (int jj = 0; jj < NJ; jj++){
    uint4 q = *(const uint4*)&Hg[((size_t)(b + jj * 4) * V_ + dst) * 512 + f8];
    const unsigned int* w = (const unsigned int*)&q;
    #pragma unroll
    for (int i = 0; i < 4; i++){
      a[jj][2 * i]     = sw * bf2f(w[i] & 0xffff);
      a[jj][2 * i + 1] = sw * bf2f(w[i] >> 16);
    }
  }
  for (int e = rs; e < re; e++){
    int s = cols[e]; float v = vals[e];
    uint4 q[NJ];
    #pragma unroll
    for (int jj = 0; jj < NJ; jj++)
      q[jj] = *(const uint4*)&Hg[((size_t)(b + jj * 4) * V_ + s) * 512 + f8];
    #pragma unroll
    for (int jj = 0; jj < NJ; jj++){
      const unsigned int* w = (const unsigned int*)&q[jj];
      #pragma unroll
      for (int i = 0; i < 4; i++){
        a[jj][2 * i]     += v * bf2f(w[i] & 0xffff);
        a[jj][2 * i + 1] += v * bf2f(w[i] >> 16);
      }
    }
  }
  #pragma unroll
  for (int jj = 0; jj < NJ; jj++){
    unsigned int o[4];
    #pragma unroll
    for (int i = 0; i < 4; i++)
      o[i] = (unsigned int)f2bf(a[jj][2 * i]) | ((unsigned int)f2bf(a[jj][2 * i + 1]) << 16);
    *(uint4*)&Xo[((size_t)(b + jj * 4) * V_ + dst) * 512 + f8] = *(uint4*)o;
  }
}

// ---------------- bf16 MFMA GEMM, m97-style global_load_lds staging ----------------
// Hg[M,N] = Xg[M,K] @ Wt^T; epilogue (cvec!=null): += wsumv[row&(V-1)]*cvec[col] + bias[col]; relu opt.
template<int BM, int BN, int WM, int WN, int TM, int TN>
__global__ __launch_bounds__(WM*WN*64) void k_gemm(
    const unsigned short* __restrict__ Xg, const unsigned short* __restrict__ Wt,
    unsigned short* __restrict__ Hg, int K, int N,
    const float* __restrict__ wsumv, const float* __restrict__ cvec,
    const float* __restrict__ bias, int relu){
  constexpr int BK = 32;
  constexpr int NW = WM * WN;
  __shared__ __align__(16) unsigned short As[BM * BK];
  __shared__ __align__(16) unsigned short Bs[BN * BK];
  const int tid = threadIdx.x;
  const int row0 = blockIdx.x * BM, col0 = blockIdx.y * BN;
  const int wave = tid >> 6, lane = tid & 63;
  const int wr = wave / WN, wc = wave % WN;
  const int lrow = lane & 15, lq = lane >> 4;
  // staging geometry: 16 rows x 32 cols per global_load_lds instr (64 lanes x 16B)
  const int lrw = lane >> 2, lcol = (lane & 3) * 8;
  constexpr int RA = BM / NW;           // A rows staged per wave
  constexpr int RB = BN / NW;
  const int arow = wave * RA, brow = wave * RB;
  f32x4 acc[TM][TN] = {};
  for (int k0 = 0; k0 < K; k0 += BK){
    __syncthreads();                    // prev iter's ds_reads done before overwrite
    #pragma unroll
    for (int t = 0; t < RA / 16; t++)
      gload16(&Xg[(size_t)(row0 + arow + t * 16 + lrw) * K + k0 + lcol],
              &As[(arow + t * 16) * BK]);
    #pragma unroll
    for (int t = 0; t < RB / 16; t++)
      gload16(&Wt[(size_t)(col0 + brow + t * 16 + lrw) * K + k0 + lcol],
              &Bs[(brow + t * 16) * BK]);
    __syncthreads();                    // drains vmcnt -> staging visible
    bf16x8 af[TM], bfr[TN];
    #pragma unroll
    for (int tm = 0; tm < TM; tm++)
      af[tm] = *(const bf16x8*)&As[(wr * TM * 16 + tm * 16 + lrow) * BK + lq * 8];
    #pragma unroll
    for (int tn = 0; tn < TN; tn++)
      bfr[tn] = *(const bf16x8*)&Bs[(wc * TN * 16 + tn * 16 + lrow) * BK + lq * 8];
    #pragma unroll
    for (int tm = 0; tm < TM; tm++)
      #pragma unroll
      for (int tn = 0; tn < TN; tn++)
        acc[tm][tn] = __builtin_amdgcn_mfma_f32_16x16x32_bf16(af[tm], bfr[tn], acc[tm][tn], 0, 0, 0);
  }
  #pragma unroll
  for (int tm = 0; tm < TM; tm++){
    #pragma unroll
    for (int tn = 0; tn < TN; tn++){
      int col = col0 + wc * TN * 16 + tn * 16 + lrow;
      float cv = 0.f, bv = 0.f;
      if (cvec){ cv = cvec[col]; bv = bias[col]; }
      #pragma unroll
      for (int r = 0; r < 4; r++){
        int row = row0 + wr * TM * 16 + tm * 16 + lq * 4 + r;
        float x = acc[tm][tn][r];
        if (cvec) x += wsumv[row & (V_ - 1)] * cv + bv;
        if (relu) x = fmaxf(x, 0.f);
        Hg[(size_t)row * N + col] = f2bf(x);
      }
    }
  }
}

// ---------------- h5 = x4 @ W56  (K=512, N=3): wave per row, coalesced + shuffle reduce ----------------
__global__ __launch_bounds__(256) void k_h5(
    const unsigned short* __restrict__ x4, const float* __restrict__ W56,
    float* __restrict__ h5){
  int m = blockIdx.x * 4 + (threadIdx.x >> 6);
  int lane = threadIdx.x & 63;
  uint4 q = *(const uint4*)&x4[(size_t)m * 512 + lane * 8];
  const unsigned int* w = (const unsigned int*)&q;
  float a0 = 0.f, a1 = 0.f, a2 = 0.f;
  #pragma unroll
  for (int i = 0; i < 8; i++){
    float x = bf2f((i & 1) ? (unsigned short)(w[i >> 1] >> 16)
                           : (unsigned short)(w[i >> 1] & 0xffff));
    int k = lane * 8 + i;
    a0 += x * W56[k * 3]; a1 += x * W56[k * 3 + 1]; a2 += x * W56[k * 3 + 2];
  }
  #pragma unroll
  for (int off = 32; off; off >>= 1){
    a0 += __shfl_down(a0, off);
    a1 += __shfl_down(a1, off);
    a2 += __shfl_down(a2, off);
  }
  if (lane == 0){
    h5[(size_t)m * 3] = a0; h5[(size_t)m * 3 + 1] = a1; h5[(size_t)m * 3 + 2] = a2;
  }
}

// ---------------- workspace layout ----------------
static constexpr size_t AL(size_t x){ return (x + 255) & ~(size_t)255; }
static constexpr size_t S512 = (size_t)M_ * 512 * 2;   // 64 MiB bf16 buffer
static constexpr size_t S3   = (size_t)M_ * 3 * 4;
static constexpr size_t OXA  = 0;                       // X buffer A / FC-head partials
static constexpr size_t OXB  = OXA  + AL(S512);         // X buffer B / precompute partials
static constexpr size_t OVA1 = OXB  + AL(S512);
static constexpr size_t OVA2 = OVA1 + AL(S3);
static constexpr size_t OH5  = OVA2 + AL(S3);
static constexpr size_t OH6  = OH5  + AL(S3);
static constexpr size_t OXF  = OH6  + AL(S3);
static constexpr size_t OFC1 = OXF  + AL(S3);
static constexpr size_t OFC2 = OFC1 + AL((size_t)B_ * 1024 * 4);
static constexpr size_t OI1  = OFC2 + AL((size_t)B_ * 1024 * 4);
static constexpr size_t OCAT = OI1  + AL((size_t)32 * 512 * 4);
static constexpr size_t OP   = OCAT + AL((size_t)36 * 512 * 4);
static constexpr size_t OC34 = OP   + AL((size_t)36 * 512 * 4);
static constexpr size_t OW56 = OC34 + AL((size_t)512 * 4);
static constexpr size_t OC56 = OW56 + AL((size_t)512 * 3 * 4);
static constexpr size_t OW3B = OC56 + AL((size_t)3 * 4);
static constexpr size_t OW4T = OW3B + AL((size_t)512 * 512 * 2);
static constexpr size_t OW34 = OW4T + AL((size_t)512 * 512 * 2);
static constexpr size_t ODEG = OW34 + AL((size_t)512 * 512 * 2);
static constexpr size_t OCNT = ODEG + AL((size_t)V_ * 4);
static constexpr size_t OROW = OCNT + AL((size_t)V_ * 4);
static constexpr size_t OCOL = OROW + AL((size_t)(V_ + 1) * 4);
static constexpr size_t OVAL = OCOL + AL((size_t)E_ * 4);
static constexpr size_t OSELF= OVAL + AL((size_t)E_ * 4);
static constexpr size_t ODINV= OSELF+ AL((size_t)V_ * 4);

extern "C" void kernel_launch(void* const* d_in, const int* in_sizes, int n_in,
                              void* d_out, int out_size, void* d_ws, size_t ws_size,
                              hipStream_t stream){
  const float* vert  = (const float*)d_in[0];
  const float* img   = (const float*)d_in[1];
  const int*   ei    = (const int*)  d_in[2];
  const float* W1 = (const float*)d_in[3],  *b1 = (const float*)d_in[4];
  const float* W2 = (const float*)d_in[5],  *b2 = (const float*)d_in[6];
  const float* W3 = (const float*)d_in[7],  *b3 = (const float*)d_in[8];
  const float* W4 = (const float*)d_in[9],  *b4 = (const float*)d_in[10];
  const float* W5 = (const float*)d_in[11], *b5 = (const float*)d_in[12];
  const float* W6 = (const float*)d_in[13], *b6 = (const float*)d_in[14];
  const float* fcW1 = (const float*)d_in[15], *fcb1 = (const float*)d_in[16];
  const float* fcW2 = (const float*)d_in[17], *fcb2 = (const float*)d_in[18];
  const float* fcW3 = (const float*)d_in[19], *fcb3 = (const float*)d_in[20];
  float* out = (float*)d_out;

  char* ws = (char*)d_ws;
  unsigned short* XA  = (unsigned short*)(ws + OXA);
  unsigned short* XB  = (unsigned short*)(ws + OXB);
  float* VA1  = (float*)(ws + OVA1);
  float* VA2  = (float*)(ws + OVA2);
  float* H5   = (float*)(ws + OH5);
  float* H6   = (float*)(ws + OH6);
  float* XF   = (float*)(ws + OXF);
  float* FC1o = (float*)(ws + OFC1);
  float* FC2o = (float*)(ws + OFC2);
  float* I1   = (float*)(ws + OI1);
  float* CAT  = (float*)(ws + OCAT);
  float* P    = (float*)(ws + OP);
  float* C34  = (float*)(ws + OC34);
  float* W56  = (float*)(ws + OW56);
  float* C56  = (float*)(ws + OC56);
  unsigned short* W3B = (unsigned short*)(ws + OW3B);
  unsigned short* W4T = (unsigned short*)(ws + OW4T);
  unsigned short* W34 = (unsigned short*)(ws + OW34);
  float* PARTA = (float*)(ws + OXA);   // FC-head partials (XA free then)
  float* PARTB = (float*)(ws + OXB);   // precompute partials (XB free then)
  int*   DEG  = (int*)(ws + ODEG);
  int*   CNT  = (int*)(ws + OCNT);
  int*   ROW  = (int*)(ws + OROW);
  int*   COL  = (int*)(ws + OCOL);
  float* VAL  = (float*)(ws + OVAL);
  float* SELF = (float*)(ws + OSELF);
  float* DINV = (float*)(ws + ODINV);
  float* WSUM = DINV + V_;     // reuse tail? no — keep separate:
  // (WSUM/W2S appended after DINV region)
  static constexpr size_t OWS  = ODINV + 0x100 * ((V_ * 4 + 255) / 0x100 * 0) + 0; // placeholder
  (void)OWS;
  float* WSUMr = (float*)(ws + ODINV + AL((size_t)V_ * 4));
  float* W2Sr  = (float*)(ws + ODINV + 2 * AL((size_t)V_ * 4));

  // ---- CSR + norm powers ----
  hipMemsetAsync(ws + ODEG, 0, OROW - ODEG, stream);
  k_deg<<<(E_ + 255) / 256, 256, 0, stream>>>(ei, DEG);
  k_scan<<<1, 64, 0, stream>>>(DEG, ROW, DINV, SELF);
  k_scatter<<<(E_ + 255) / 256, 256, 0, stream>>>(ei, ROW, CNT, COL, VAL, DINV);
  k_wsum<<<(V_ + 255) / 256, 256, 0, stream>>>(ROW, VAL, SELF, WSUMr);
  k_w2<<<(V_ + 255) / 256, 256, 0, stream>>>(ROW, COL, VAL, SELF, WSUMr, W2Sr);

  // ---- weight precompute ----
  k_cvt<<<(512 * 512 + 255) / 256, 256, 0, stream>>>(W3, W3B, 512 * 512);
  k_wt<<<(512 * 512 + 255) / 256, 256, 0, stream>>>(W4, W4T, 512, 512);
  // W34T[n][k3] = sum_k W4T[n,k] * W3[k3,k]
  k_gemm<128,128,2,2,4,4><<<dim3(4, 4), 256, 0, stream>>>(W4T, W3B, W34, 512, 512,
                                                          nullptr, nullptr, nullptr, 0);
  // I1 = img @ W1[3:,:]
  k_fcp<32,64><<<dim3(2, 8), 256, 0, stream>>>(img, W1 + 3 * 512, PARTB, 512, 512);
  k_fcr<<<(32 * 512 + 255) / 256, 256, 0, stream>>>(PARTB, nullptr, I1, 32 * 512, 512, 8, 0, nullptr);
  // P = [b1; W1[0:3]; I1] @ W2
  k_cat36<<<(36 * 512 + 255) / 256, 256, 0, stream>>>(b1, W1, I1, CAT);
  k_fcp<36,64><<<dim3(2, 8), 256, 0, stream>>>(CAT, W2, PARTB, 512, 512);
  k_fcr<<<(36 * 512 + 255) / 256, 256, 0, stream>>>(PARTB, nullptr, P, 36 * 512, 512, 8, 0, nullptr);
  // tiny tails
  k_vm<<<2, 256, 0, stream>>>(b3, W4, C34, 1, 512, 512);
  k_vm<<<6, 256, 0, stream>>>(W5, W6, W56, 512, 64, 3);
  k_vm<<<1, 256, 0, stream>>>(b5, W6, C56, 1, 64, 3);

  // ---- layers 1+2 ----
  k_agg3f<<<M_ / 256, 256, 0, stream>>>(vert, ROW, COL, VAL, SELF, VA1, nullptr, nullptr, 0);
  k_agg3f<<<M_ / 256, 256, 0, stream>>>(VA1, ROW, COL, VAL, SELF, VA2, nullptr, nullptr, 0);
  k_x2<<<M_ / 4, 256, 0, stream>>>(VA2, P, WSUMr, W2Sr, b2, XA);

  // ---- layers 3+4 ----
  k_aggb<16><<<dim3(V_, 2), 256, 0, stream>>>(XA, ROW, COL, VAL, SELF, XB);
  k_aggb<16><<<dim3(V_, 2), 256, 0, stream>>>(XB, ROW, COL, VAL, SELF, XA);
  k_gemm<128,128,2,2,4,4><<<dim3(M_ / 128, 4), 256, 0, stream>>>(XA, W34, XB, 512, 512,
                                                                 WSUMr, C34, b4, 1);

  // ---- layers 5+6 ----
  k_h5<<<M_ / 4, 256, 0, stream>>>(XB, W56, H5);
  k_agg3f<<<M_ / 256, 256, 0, stream>>>(H5, ROW, COL, VAL, SELF, H6, nullptr, nullptr, 0);
  k_agg3f<<<M_ / 256, 256, 0, stream>>>(H6, ROW, COL, VAL, SELF, XF, C56, b6, 1);

  // ---- FC head ----
  k_fcp<32,64><<<dim3(4, 96), 256, 0, stream>>>(XF, fcW1, PARTA, 6144, 1024);
  k_fcr<<<(B_ * 1024 + 255) / 256, 256, 0, stream>>>(PARTA, fcb1, FC1o, 32 * 1024, 1024, 96, 0, nullptr);
  k_fcp<32,64><<<dim3(4, 16), 256, 0, stream>>>(FC1o, fcW2, PARTA, 1024, 1024);
  k_fcr<<<(B_ * 1024 + 255) / 256, 256, 0, stream>>>(PARTA, fcb2, FC2o, 32 * 1024, 1024, 16, 0, nullptr);
  k_fcp<32,64><<<dim3(24, 16), 256, 0, stream>>>(FC2o, fcW3, PARTA, 1024, 6144);
  k_fcr<<<(B_ * 6144 + 255) / 256, 256, 0, stream>>>(PARTA, fcb3, out, 32 * 6144, 6144, 16, 1, vert);
}